// Round 9
// baseline (251.767 us; speedup 1.0000x reference)
//
#include <hip/hip_runtime.h>
#include <float.h>

// z: (64,32,32,64) fp32 -> N=65536 rows, D=64 ; codebook: (1024,64) fp32
// out concat fp32: zq [N*64] | tokens-as-float [N] | codebook [1024*64]
constexpr int D     = 64;
constexpr int V     = 1024;
constexpr int NROWS = 65536;
// Split-f16 screen (zh*ch + zh*cl + zl*ch); MARGIN certifies argmin.
constexpr float MARGIN = 0.01f;

typedef _Float16 half8 __attribute__((ext_vector_type(8)));
typedef float    f32x4 __attribute__((ext_vector_type(4)));

// ---------------- prep: convert codebook ONCE (verbatim, passed) -------------
__global__ __launch_bounds__(256) void vq_prep(
    const float* __restrict__ cb, _Float16* __restrict__ wsH,
    _Float16* __restrict__ wsL, float* __restrict__ c2,
    float* __restrict__ cbout, int* __restrict__ cnt) {
  const int gid = blockIdx.x * 256 + threadIdx.x;   // 0..16383
  if (gid == 0) cnt[0] = 0;

  ((float4*)cbout)[gid] = ((const float4*)cb)[gid];

  if (gid < V) {
    const int cw = gid;
    const float* src = cb + (size_t)cw * D;
    float part = 0.f;
#pragma unroll
    for (int chunk = 0; chunk < 8; ++chunk) {
      float4 q0 = ((const float4*)(src + chunk * 8))[0];
      float4 q1 = ((const float4*)(src + chunk * 8))[1];
      float xs[8] = {q0.x, q0.y, q0.z, q0.w, q1.x, q1.y, q1.z, q1.w};
      half8 hh, hl;
#pragma unroll
      for (int e = 0; e < 8; ++e) {
        _Float16 hi = (_Float16)xs[e];
        hh[e] = hi;
        hl[e] = (_Float16)(xs[e] - (float)hi);
        part  = fmaf(xs[e], xs[e], part);
      }
      *(half8*)&wsH[((size_t)chunk * V + cw) * 8] = hh;
      *(half8*)&wsL[((size_t)chunk * V + cw) * 8] = hl;
    }
    c2[cw] = part;
  }
}

// ---------------- screen: 512-thread blocks (8 waves share staging) ----------
// vs R8 (passed, <43us): block width 256 -> 512, grid 1024 -> 512. Waves/CU
// unchanged (2 blocks x 8 waves = 16); per-CU staging traffic HALVES (8 waves
// now share each 16 KiB half-phase stage instead of 4). Per-wave compute,
// dbuf structure, codeword visit order, update math (acc-split + fmed3),
// tie-breaks, margin: all verbatim R8 / bit-identical per row.
__global__ __launch_bounds__(512, 4) void vq_screen(
    const float* __restrict__ z, const float* __restrict__ cb,
    const _Float16* __restrict__ wsH, const _Float16* __restrict__ wsL,
    const float* __restrict__ c2g,
    float* __restrict__ zq, float* __restrict__ tok,
    int* __restrict__ cnt, int* __restrict__ list) {
  __shared__ __align__(16) _Float16 sBh[2][8][64][8];  // 2 x 8 KiB
  __shared__ __align__(16) _Float16 sBl[2][8][64][8];  // 2 x 8 KiB
  __shared__ __align__(16) float sC2a[1024];           // 4 KiB (all phases)
  __shared__ int   sW[8][16];
  __shared__ int   sFlagRows[128];
  __shared__ int   sFlagCnt, sFlagBase;

  const int tid  = threadIdx.x;
  const int lane = tid & 63;
  const int wv   = tid >> 6;        // wave 0..7
  const int l15  = lane & 15;
  const int quad = lane >> 4;
  const int gw   = blockIdx.x * 8 + wv;   // 0..4095
  const int rowbase = gw * 16;

  if (tid == 0) sFlagCnt = 0;

  // A fragments hi/lo: row rowbase + l15, k = quad*8 + j (+32*h)  [r4-proven]
  half8 afh[2], afl[2];
  {
    const float* zr = z + (size_t)(rowbase + l15) * D;
#pragma unroll
    for (int h = 0; h < 2; ++h) {
      const float4* p = (const float4*)(zr + h * 32 + quad * 8);
      float4 q0 = p[0], q1 = p[1];
      float xs[8] = {q0.x, q0.y, q0.z, q0.w, q1.x, q1.y, q1.z, q1.w};
      half8 ah, al;
#pragma unroll
      for (int e = 0; e < 8; ++e) {
        _Float16 hi = (_Float16)xs[e];
        ah[e] = hi;
        al[e] = (_Float16)(xs[e] - (float)hi);
      }
      afh[h] = ah; afl[h] = al;
    }
  }

  float b1[4], b2[4]; int i1[4];
#pragma unroll
  for (int r = 0; r < 4; ++r) { b1[r] = FLT_MAX; b2[r] = FLT_MAX; i1[r] = 0; }

  // ---- prologue: all c2 values + stage half-phase 0 into buf 0 ----
  {
    float2 qc = ((const float2*)c2g)[tid];     // 512 threads x float2 = 1024
    *(float2*)&sC2a[tid * 2] = qc;
  }
#pragma unroll
  for (int i = 0; i < 2; ++i) {
    const int idx   = i * 512 + tid;   // 0..1023
    const int seg   = idx >> 6;        // 0..15 (0..7 hi, 8..15 lo)
    const int off   = idx & 63;
    const int chunk = seg & 7;
    const _Float16* srcb = (seg < 8) ? wsH : wsL;
    const half8 v = *(const half8*)&srcb[((size_t)chunk * V + off) * 8];  // hp 0
    if (seg < 8) *(half8*)&sBh[0][chunk][off][0] = v;
    else         *(half8*)&sBl[0][chunk][off][0] = v;
  }
  __syncthreads();

  for (int hp = 0; hp < 16; ++hp) {
    const int cur = hp & 1;
    const int nxt = cur ^ 1;
    // ---- issue next half-phase's 16 KiB into registers ----
    half8 pre[2];
    if (hp < 15) {
#pragma unroll
      for (int i = 0; i < 2; ++i) {
        const int idx   = i * 512 + tid;
        const int seg   = idx >> 6;
        const int off   = idx & 63;
        const int chunk = seg & 7;
        const _Float16* srcb = (seg < 8) ? wsH : wsL;
        pre[i] = *(const half8*)&srcb[((size_t)chunk * V + (hp + 1) * 64 + off) * 8];
      }
    }
    // ---- compute on current buffer: 4 col-tiles of 16 codewords ----
#pragma unroll
    for (int tl = 0; tl < 4; ++tl) {
      const int cwl  = tl * 16 + l15;          // 0..63
      const int vcol = hp * 64 + cwl;
      const float c2v = sC2a[hp * 64 + cwl];
      half8 bh0 = *(const half8*)&sBh[cur][quad][cwl][0];      // k = quad*8+j
      half8 bh1 = *(const half8*)&sBh[cur][4 + quad][cwl][0];  // k = 32+quad*8+j
      half8 bl0 = *(const half8*)&sBl[cur][quad][cwl][0];
      half8 bl1 = *(const half8*)&sBl[cur][4 + quad][cwl][0];
      // two independent 3-chains (2x MFMA ILP), summed once
      f32x4 acc1 = {0.f, 0.f, 0.f, 0.f};
      f32x4 acc2 = {0.f, 0.f, 0.f, 0.f};
      acc1 = __builtin_amdgcn_mfma_f32_16x16x32_f16(afh[0], bh0, acc1, 0, 0, 0);
      acc2 = __builtin_amdgcn_mfma_f32_16x16x32_f16(afh[1], bh1, acc2, 0, 0, 0);
      acc1 = __builtin_amdgcn_mfma_f32_16x16x32_f16(afh[0], bl0, acc1, 0, 0, 0);
      acc2 = __builtin_amdgcn_mfma_f32_16x16x32_f16(afh[1], bl1, acc2, 0, 0, 0);
      acc1 = __builtin_amdgcn_mfma_f32_16x16x32_f16(afl[0], bh0, acc1, 0, 0, 0);
      acc2 = __builtin_amdgcn_mfma_f32_16x16x32_f16(afl[1], bh1, acc2, 0, 0, 0);
#pragma unroll
      for (int r = 0; r < 4; ++r) {
        float m0 = fmaf(-2.f, acc1[r] + acc2[r], c2v);
        bool  c0 = m0 < b1[r];
        b2[r] = __builtin_amdgcn_fmed3f(m0, b1[r], b2[r]);  // == min(max(m0,b1),b2)
        b1[r] = fminf(b1[r], m0);
        i1[r] = c0 ? vcol : i1[r];
      }
    }
    // ---- commit prefetched half-phase into the IDLE buffer ----
    if (hp < 15) {
#pragma unroll
      for (int i = 0; i < 2; ++i) {
        const int idx   = i * 512 + tid;
        const int seg   = idx >> 6;
        const int off   = idx & 63;
        const int chunk = seg & 7;
        if (seg < 8) *(half8*)&sBh[nxt][chunk][off][0] = pre[i];
        else         *(half8*)&sBl[nxt][chunk][off][0] = pre[i];
      }
    }
    __syncthreads();
  }

  // ---- reduce over the 16 col-lanes of each quad group ----
#pragma unroll
  for (int r = 0; r < 4; ++r) {
    float v1 = b1[r], v2 = b2[r]; int ix = i1[r];
#pragma unroll
    for (int s = 1; s < 16; s <<= 1) {
      float ov1 = __shfl_xor(v1, s);
      float ov2 = __shfl_xor(v2, s);
      int   oix = __shfl_xor(ix, s);
      bool take = (ov1 < v1) || (ov1 == v1 && oix < ix);  // first-occurrence ties
      float worse = take ? v1 : ov1;
      v2 = fminf(fminf(v2, ov2), worse);
      v1 = take ? ov1 : v1;
      ix = take ? oix : ix;
    }
    b1[r] = v1; b2[r] = v2; i1[r] = ix;
  }

  if (l15 == 0) {
#pragma unroll
    for (int r = 0; r < 4; ++r) {
      int rl = quad * 4 + r;              // row within wave tile
      sW[wv][rl] = i1[r];
      if (b2[r] - b1[r] < MARGIN) {
        int s = atomicAdd(&sFlagCnt, 1);
        sFlagRows[s] = rowbase + rl;      // global row
      }
    }
  }
  __syncthreads();
  if (tid == 0 && sFlagCnt > 0) sFlagBase = atomicAdd(cnt, sFlagCnt);
  __syncthreads();
  if (tid < sFlagCnt) list[sFlagBase + tid] = sFlagRows[tid];

  // tokens (as float): 128 rows per block
  if (tid < 128) tok[blockIdx.x * 128 + tid] = (float)sW[tid >> 4][tid & 15];

  // zq gather: 128 rows x 16 chunks of 16B = 2048 float4 over 512 threads
#pragma unroll
  for (int i = 0; i < 4; ++i) {
    int cid = i * 512 + tid;
    int r = cid >> 4, seg = cid & 15;
    int widx = sW[r >> 4][r & 15];
    float4 val = *(const float4*)(cb + (size_t)widx * D + seg * 4);
    *(float4*)(zq + (size_t)(blockIdx.x * 128 + r) * D + seg * 4) = val;
  }
}

// ---------------- exact fp32 fallback: same math, 2-barrier reduction --------
// Per-thread 4-cw scan is verbatim. Reduction: wave shfl_xor (same tie-break
// predicate, associative min-with-index) + one cross-wave LDS step -> 2
// barriers instead of 9.
__global__ __launch_bounds__(256) void vq_fallback(
    const float* __restrict__ z, const float* __restrict__ cb,
    const int* __restrict__ cnt, const int* __restrict__ list,
    float* __restrict__ zq, float* __restrict__ tok) {
  __shared__ float sRv[4];
  __shared__ int   sRi[4];
  __shared__ int   sWin;
  const int t = threadIdx.x;
  const int wv = t >> 6;
  const int ln = t & 63;
  const int n = cnt[0];
  for (int it = blockIdx.x; it < n; it += gridDim.x) {
    int row = __builtin_amdgcn_readfirstlane(list[it]);
    const float* zr = z + (size_t)row * D;
    float zreg[D];
#pragma unroll
    for (int i = 0; i < D / 4; ++i) {
      float4 q = ((const float4*)zr)[i];
      zreg[4 * i] = q.x; zreg[4 * i + 1] = q.y; zreg[4 * i + 2] = q.z; zreg[4 * i + 3] = q.w;
    }
    float d1 = 0.f;
#pragma unroll
    for (int i = 0; i < D; ++i) d1 = fmaf(zreg[i], zreg[i], d1);
    float best = FLT_MAX; int bidx = 0;
    for (int c = 0; c < 4; ++c) {
      int v = t + 256 * c;
      const float* cp = cb + (size_t)v * D;
      float acc = 0.f, cc = 0.f;
#pragma unroll
      for (int dd = 0; dd < D; ++dd) {
        acc = fmaf(zreg[dd], cp[dd], acc);
        cc  = fmaf(cp[dd], cp[dd], cc);
      }
      float dist = (d1 + cc) - 2.f * acc;
      if (dist < best || (dist == best && v < bidx)) { best = dist; bidx = v; }
    }
    // wave reduction (min, first-occurrence ties)
#pragma unroll
    for (int s = 1; s < 64; s <<= 1) {
      float ov = __shfl_xor(best, s);
      int   oi = __shfl_xor(bidx, s);
      if (ov < best || (ov == best && oi < bidx)) { best = ov; bidx = oi; }
    }
    if (ln == 0) { sRv[wv] = best; sRi[wv] = bidx; }
    __syncthreads();
    if (t == 0) {
      float bv = sRv[0]; int bi = sRi[0];
#pragma unroll
      for (int w = 1; w < 4; ++w) {
        float ov = sRv[w]; int oi = sRi[w];
        if (ov < bv || (ov == bv && oi < bi)) { bv = ov; bi = oi; }
      }
      sWin = bi;
      tok[row] = (float)bi;
    }
    __syncthreads();
    int win = sWin;
    if (t < 16) {
      float4 q = ((const float4*)(cb + (size_t)win * D))[t];
      ((float4*)(zq + (size_t)row * D))[t] = q;
    }
    __syncthreads();  // sRv/sRi/sWin reused next iteration
  }
}

extern "C" void kernel_launch(void* const* d_in, const int* in_sizes, int n_in,
                              void* d_out, int out_size, void* d_ws, size_t ws_size,
                              hipStream_t stream) {
  const float* z  = (const float*)d_in[0];
  const float* cb = (const float*)d_in[1];

  float* out = (float*)d_out;
  float* zq  = out;                      // [NROWS*D]
  float* tok = out + (size_t)NROWS * D;  // [NROWS]
  float* cbo = tok + NROWS;              // [V*D]

  // ws layout: wsH 128K | wsL 128K | c2 4K | cnt 256B | list 256K
  char* wsb = (char*)d_ws;
  _Float16* wsH  = (_Float16*)(wsb + 0);
  _Float16* wsL  = (_Float16*)(wsb + 131072);
  float*    c2   = (float*)(wsb + 262144);
  int*      cnt  = (int*)(wsb + 266240);
  int*      list = (int*)(wsb + 266496);

  vq_prep<<<64, 256, 0, stream>>>(cb, wsH, wsL, c2, cbo, cnt);
  vq_screen<<<512, 512, 0, stream>>>(z, cb, wsH, wsL, c2, zq, tok, cnt, list);
  vq_fallback<<<1024, 256, 0, stream>>>(z, cb, cnt, list, zq, tok);
}

// Round 10
// 127.500 us; speedup vs baseline: 1.9746x; 1.9746x over previous
//
#include <hip/hip_runtime.h>
#include <float.h>

// z: (64,32,32,64) fp32 -> N=65536 rows, D=64 ; codebook: (1024,64) fp32
// out concat fp32: zq [N*64] | tokens-as-float [N] | codebook [1024*64]
constexpr int D     = 64;
constexpr int V     = 1024;
constexpr int NROWS = 65536;
// Split-f16 screen (zh*ch + zh*cl + zl*ch); MARGIN certifies argmin.
constexpr float MARGIN = 0.01f;

typedef _Float16 half8 __attribute__((ext_vector_type(8)));
typedef float    f32x4 __attribute__((ext_vector_type(4)));

// ---------------- prep: convert codebook ONCE (verbatim, passed) -------------
__global__ __launch_bounds__(256) void vq_prep(
    const float* __restrict__ cb, _Float16* __restrict__ wsH,
    _Float16* __restrict__ wsL, float* __restrict__ c2,
    float* __restrict__ cbout, int* __restrict__ cnt) {
  const int gid = blockIdx.x * 256 + threadIdx.x;   // 0..16383
  if (gid == 0) cnt[0] = 0;

  ((float4*)cbout)[gid] = ((const float4*)cb)[gid];

  if (gid < V) {
    const int cw = gid;
    const float* src = cb + (size_t)cw * D;
    float part = 0.f;
#pragma unroll
    for (int chunk = 0; chunk < 8; ++chunk) {
      float4 q0 = ((const float4*)(src + chunk * 8))[0];
      float4 q1 = ((const float4*)(src + chunk * 8))[1];
      float xs[8] = {q0.x, q0.y, q0.z, q0.w, q1.x, q1.y, q1.z, q1.w};
      half8 hh, hl;
#pragma unroll
      for (int e = 0; e < 8; ++e) {
        _Float16 hi = (_Float16)xs[e];
        hh[e] = hi;
        hl[e] = (_Float16)(xs[e] - (float)hi);
        part  = fmaf(xs[e], xs[e], part);
      }
      *(half8*)&wsH[((size_t)chunk * V + cw) * 8] = hh;
      *(half8*)&wsL[((size_t)chunk * V + cw) * 8] = hl;
    }
    c2[cw] = part;
  }
}

// ---------------- screen: R8 build VERBATIM (best passing, 130.25us) ---------
// 256 threads, 1024 blocks, dbuf half-phases, acc-split + fmed3/fminf updates.
// R9's 512-thread variant corrupted the margin state (fallback n exploded to
// ~all rows, FETCH 106MB) -- reverted. Do NOT widen blocks without isolating
// the flag-path regression first.
__global__ __launch_bounds__(256, 4) void vq_screen(
    const float* __restrict__ z, const float* __restrict__ cb,
    const _Float16* __restrict__ wsH, const _Float16* __restrict__ wsL,
    const float* __restrict__ c2g,
    float* __restrict__ zq, float* __restrict__ tok,
    int* __restrict__ cnt, int* __restrict__ list) {
  __shared__ __align__(16) _Float16 sBh[2][8][64][8];  // 2 x 8 KiB
  __shared__ __align__(16) _Float16 sBl[2][8][64][8];  // 2 x 8 KiB
  __shared__ __align__(16) float sC2a[1024];           // 4 KiB (all phases)
  __shared__ int   sW[4][16];
  __shared__ int   sFlagRows[64];
  __shared__ int   sFlagCnt, sFlagBase;

  const int tid  = threadIdx.x;
  const int lane = tid & 63;
  const int wv   = tid >> 6;        // wave 0..3
  const int l15  = lane & 15;
  const int quad = lane >> 4;
  const int gw   = blockIdx.x * 4 + wv;   // 0..4095
  const int rowbase = gw * 16;

  if (tid == 0) sFlagCnt = 0;

  // A fragments hi/lo: row rowbase + l15, k = quad*8 + j (+32*h)  [r4-proven]
  half8 afh[2], afl[2];
  {
    const float* zr = z + (size_t)(rowbase + l15) * D;
#pragma unroll
    for (int h = 0; h < 2; ++h) {
      const float4* p = (const float4*)(zr + h * 32 + quad * 8);
      float4 q0 = p[0], q1 = p[1];
      float xs[8] = {q0.x, q0.y, q0.z, q0.w, q1.x, q1.y, q1.z, q1.w};
      half8 ah, al;
#pragma unroll
      for (int e = 0; e < 8; ++e) {
        _Float16 hi = (_Float16)xs[e];
        ah[e] = hi;
        al[e] = (_Float16)(xs[e] - (float)hi);
      }
      afh[h] = ah; afl[h] = al;
    }
  }

  float b1[4], b2[4]; int i1[4];
#pragma unroll
  for (int r = 0; r < 4; ++r) { b1[r] = FLT_MAX; b2[r] = FLT_MAX; i1[r] = 0; }

  // ---- prologue: all c2 values + stage half-phase 0 into buf 0 ----
  {
    float4 qc = ((const float4*)c2g)[tid];     // 256 threads x float4 = 1024
    *(float4*)&sC2a[tid * 4] = qc;
  }
#pragma unroll
  for (int i = 0; i < 4; ++i) {
    const int idx   = i * 256 + tid;   // 0..1023
    const int seg   = idx >> 6;        // 0..15 (0..7 hi, 8..15 lo)
    const int off   = idx & 63;
    const int chunk = seg & 7;
    const _Float16* srcb = (seg < 8) ? wsH : wsL;
    const half8 v = *(const half8*)&srcb[((size_t)chunk * V + off) * 8];  // hp 0
    if (seg < 8) *(half8*)&sBh[0][chunk][off][0] = v;
    else         *(half8*)&sBl[0][chunk][off][0] = v;
  }
  __syncthreads();

  for (int hp = 0; hp < 16; ++hp) {
    const int cur = hp & 1;
    const int nxt = cur ^ 1;
    // ---- issue next half-phase's 16 KiB into registers ----
    half8 pre[4];
    if (hp < 15) {
#pragma unroll
      for (int i = 0; i < 4; ++i) {
        const int idx   = i * 256 + tid;
        const int seg   = idx >> 6;
        const int off   = idx & 63;
        const int chunk = seg & 7;
        const _Float16* srcb = (seg < 8) ? wsH : wsL;
        pre[i] = *(const half8*)&srcb[((size_t)chunk * V + (hp + 1) * 64 + off) * 8];
      }
    }
    // ---- compute on current buffer: 4 col-tiles of 16 codewords ----
#pragma unroll
    for (int tl = 0; tl < 4; ++tl) {
      const int cwl  = tl * 16 + l15;          // 0..63
      const int vcol = hp * 64 + cwl;
      const float c2v = sC2a[hp * 64 + cwl];
      half8 bh0 = *(const half8*)&sBh[cur][quad][cwl][0];      // k = quad*8+j
      half8 bh1 = *(const half8*)&sBh[cur][4 + quad][cwl][0];  // k = 32+quad*8+j
      half8 bl0 = *(const half8*)&sBl[cur][quad][cwl][0];
      half8 bl1 = *(const half8*)&sBl[cur][4 + quad][cwl][0];
      // two independent 3-chains (2x MFMA ILP), summed once
      f32x4 acc1 = {0.f, 0.f, 0.f, 0.f};
      f32x4 acc2 = {0.f, 0.f, 0.f, 0.f};
      acc1 = __builtin_amdgcn_mfma_f32_16x16x32_f16(afh[0], bh0, acc1, 0, 0, 0);
      acc2 = __builtin_amdgcn_mfma_f32_16x16x32_f16(afh[1], bh1, acc2, 0, 0, 0);
      acc1 = __builtin_amdgcn_mfma_f32_16x16x32_f16(afh[0], bl0, acc1, 0, 0, 0);
      acc2 = __builtin_amdgcn_mfma_f32_16x16x32_f16(afh[1], bl1, acc2, 0, 0, 0);
      acc1 = __builtin_amdgcn_mfma_f32_16x16x32_f16(afl[0], bh0, acc1, 0, 0, 0);
      acc2 = __builtin_amdgcn_mfma_f32_16x16x32_f16(afl[1], bh1, acc2, 0, 0, 0);
#pragma unroll
      for (int r = 0; r < 4; ++r) {
        float m0 = fmaf(-2.f, acc1[r] + acc2[r], c2v);
        bool  c0 = m0 < b1[r];
        b2[r] = __builtin_amdgcn_fmed3f(m0, b1[r], b2[r]);  // == min(max(m0,b1),b2)
        b1[r] = fminf(b1[r], m0);
        i1[r] = c0 ? vcol : i1[r];
      }
    }
    // ---- commit prefetched half-phase into the IDLE buffer ----
    if (hp < 15) {
#pragma unroll
      for (int i = 0; i < 4; ++i) {
        const int idx   = i * 256 + tid;
        const int seg   = idx >> 6;
        const int off   = idx & 63;
        const int chunk = seg & 7;
        if (seg < 8) *(half8*)&sBh[nxt][chunk][off][0] = pre[i];
        else         *(half8*)&sBl[nxt][chunk][off][0] = pre[i];
      }
    }
    __syncthreads();
  }

  // ---- reduce over the 16 col-lanes of each quad group ----
#pragma unroll
  for (int r = 0; r < 4; ++r) {
    float v1 = b1[r], v2 = b2[r]; int ix = i1[r];
#pragma unroll
    for (int s = 1; s < 16; s <<= 1) {
      float ov1 = __shfl_xor(v1, s);
      float ov2 = __shfl_xor(v2, s);
      int   oix = __shfl_xor(ix, s);
      bool take = (ov1 < v1) || (ov1 == v1 && oix < ix);  // first-occurrence ties
      float worse = take ? v1 : ov1;
      v2 = fminf(fminf(v2, ov2), worse);
      v1 = take ? ov1 : v1;
      ix = take ? oix : ix;
    }
    b1[r] = v1; b2[r] = v2; i1[r] = ix;
  }

  if (l15 == 0) {
#pragma unroll
    for (int r = 0; r < 4; ++r) {
      int rl = quad * 4 + r;              // row within wave tile
      sW[wv][rl] = i1[r];
      if (b2[r] - b1[r] < MARGIN) {
        int s = atomicAdd(&sFlagCnt, 1);
        sFlagRows[s] = rowbase + rl;      // global row
      }
    }
  }
  __syncthreads();
  if (tid == 0 && sFlagCnt > 0) sFlagBase = atomicAdd(cnt, sFlagCnt);
  __syncthreads();
  if (tid < sFlagCnt) list[sFlagBase + tid] = sFlagRows[tid];

  // tokens (as float): 64 rows per block
  if (tid < 64) tok[blockIdx.x * 64 + tid] = (float)sW[tid >> 4][tid & 15];

  // zq gather: 64 rows x 16 chunks of 16B = 1024 float4 over 256 threads
#pragma unroll
  for (int i = 0; i < 4; ++i) {
    int cid = i * 256 + tid;
    int r = cid >> 4, seg = cid & 15;
    int widx = sW[r >> 4][r & 15];
    float4 val = *(const float4*)(cb + (size_t)widx * D + seg * 4);
    *(float4*)(zq + (size_t)(blockIdx.x * 64 + r) * D + seg * 4) = val;
  }
}

// ---------------- exact fp32 fallback: VERBATIM tree version (passed) --------
__global__ __launch_bounds__(256) void vq_fallback(
    const float* __restrict__ z, const float* __restrict__ cb,
    const int* __restrict__ cnt, const int* __restrict__ list,
    float* __restrict__ zq, float* __restrict__ tok) {
  __shared__ float sv[256];
  __shared__ int   si[256];
  const int t = threadIdx.x;
  const int n = cnt[0];
  for (int it = blockIdx.x; it < n; it += gridDim.x) {
    int row = __builtin_amdgcn_readfirstlane(list[it]);
    const float* zr = z + (size_t)row * D;
    float zreg[D];
#pragma unroll
    for (int i = 0; i < D / 4; ++i) {
      float4 q = ((const float4*)zr)[i];
      zreg[4 * i] = q.x; zreg[4 * i + 1] = q.y; zreg[4 * i + 2] = q.z; zreg[4 * i + 3] = q.w;
    }
    float d1 = 0.f;
#pragma unroll
    for (int i = 0; i < D; ++i) d1 = fmaf(zreg[i], zreg[i], d1);
    float best = FLT_MAX; int bidx = 0;
    for (int c = 0; c < 4; ++c) {
      int v = t + 256 * c;
      const float* cp = cb + (size_t)v * D;
      float acc = 0.f, cc = 0.f;
#pragma unroll
      for (int dd = 0; dd < D; ++dd) {
        acc = fmaf(zreg[dd], cp[dd], acc);
        cc  = fmaf(cp[dd], cp[dd], cc);
      }
      float dist = (d1 + cc) - 2.f * acc;
      if (dist < best) { best = dist; bidx = v; }
    }
    sv[t] = best; si[t] = bidx;
    __syncthreads();
    for (int s = 128; s > 0; s >>= 1) {
      if (t < s) {
        float v2 = sv[t + s]; int i2 = si[t + s];
        if (v2 < sv[t] || (v2 == sv[t] && i2 < si[t])) { sv[t] = v2; si[t] = i2; }
      }
      __syncthreads();
    }
    int win = si[0];
    if (t == 0) tok[row] = (float)win;
    if (t < 16) {
      float4 q = ((const float4*)(cb + (size_t)win * D))[t];
      ((float4*)(zq + (size_t)row * D))[t] = q;
    }
    __syncthreads();  // sv/si reused next iteration
  }
}

extern "C" void kernel_launch(void* const* d_in, const int* in_sizes, int n_in,
                              void* d_out, int out_size, void* d_ws, size_t ws_size,
                              hipStream_t stream) {
  const float* z  = (const float*)d_in[0];
  const float* cb = (const float*)d_in[1];

  float* out = (float*)d_out;
  float* zq  = out;                      // [NROWS*D]
  float* tok = out + (size_t)NROWS * D;  // [NROWS]
  float* cbo = tok + NROWS;              // [V*D]

  // ws layout: wsH 128K | wsL 128K | c2 4K | cnt 256B | list 256K
  char* wsb = (char*)d_ws;
  _Float16* wsH  = (_Float16*)(wsb + 0);
  _Float16* wsL  = (_Float16*)(wsb + 131072);
  float*    c2   = (float*)(wsb + 262144);
  int*      cnt  = (int*)(wsb + 266240);
  int*      list = (int*)(wsb + 266496);

  vq_prep<<<64, 256, 0, stream>>>(cb, wsH, wsL, c2, cbo, cnt);
  vq_screen<<<1024, 256, 0, stream>>>(z, cb, wsH, wsL, c2, zq, tok, cnt, list);
  vq_fallback<<<1024, 256, 0, stream>>>(z, cb, cnt, list, zq, tok);
}